// Round 1
// baseline (278.377 us; speedup 1.0000x reference)
//
#include <hip/hip_runtime.h>
#include <stdint.h>
#include <math.h>

#define TIECAP 4096

struct Ctrl {
  unsigned long long prefix;   // accumulates the selected key (threshold T)
  int rank_rem;                // remaining 0-indexed rank within matching subset
  int L;                       // count of keys < T
  int tie_count;               // count of keys == T
  int num_rm;                  // number of edges to prune
  int pad;
};

// Map double -> uint64 so that unsigned compare == double ascending compare.
__device__ __forceinline__ unsigned long long dkey(double d) {
  unsigned long long u = (unsigned long long)__double_as_longlong(d);
  return (u & 0x8000000000000000ull) ? ~u : (u | 0x8000000000000000ull);
}

__global__ void k_init(unsigned int* hist8, Ctrl* ctrl, int num_rm) {
  int t = blockIdx.x * blockDim.x + threadIdx.x;
  if (t < 8 * 256) hist8[t] = 0u;
  if (t == 0) {
    ctrl->prefix = 0ull;
    ctrl->rank_rem = num_rm - 1;   // 0-indexed rank of the largest pruned key
    ctrl->L = 0;
    ctrl->tie_count = 0;
    ctrl->num_rm = num_rm;
  }
}

// key[e] = orderable bits of exact f64 sum wm[src,dst]+wm[dst,src] (batch 0 edges)
__global__ void k_keys(const int* __restrict__ ei, const float* __restrict__ wm,
                       int N, long long E, int D,
                       unsigned long long* __restrict__ keys) {
  int e = blockIdx.x * blockDim.x + threadIdx.x;
  if (e >= N) return;
  int src = ei[e];
  int dst = ei[E + e];
  double s = (double)wm[(long long)src * D + dst] + (double)wm[(long long)dst * D + src];
  keys[e] = dkey(s);
}

// Histogram of 8-bit digit `level` among elements whose higher bits match prefix.
__global__ void k_hist(const unsigned long long* __restrict__ keys, int N, int level,
                       const Ctrl* __restrict__ ctrl, unsigned int* __restrict__ hist) {
  __shared__ unsigned int sh[256];
  if (threadIdx.x < 256) sh[threadIdx.x] = 0u;
  __syncthreads();
  int e = blockIdx.x * blockDim.x + threadIdx.x;
  int shift = 56 - 8 * level;
  if (e < N) {
    unsigned long long k = keys[e];
    bool match;
    if (level == 0) {
      match = true;
    } else {
      unsigned long long prefix = ctrl->prefix;
      match = (((k ^ prefix) >> (shift + 8)) == 0ull);
    }
    if (match) atomicAdd(&sh[(unsigned int)(k >> shift) & 0xFFu], 1u);
  }
  __syncthreads();
  if (threadIdx.x < 256 && sh[threadIdx.x]) atomicAdd(&hist[threadIdx.x], sh[threadIdx.x]);
}

// Walk 256 bins, find the bin containing the remaining rank; extend prefix.
__global__ void k_pick(const unsigned int* __restrict__ hist, int level, Ctrl* ctrl) {
  if (threadIdx.x != 0 || blockIdx.x != 0) return;
  unsigned long long r = (unsigned long long)ctrl->rank_rem;
  int shift = 56 - 8 * level;
  unsigned long long cum = 0;
  for (int b = 0; b < 256; ++b) {
    unsigned long long c = (unsigned long long)hist[b];
    if (cum + c > r) {
      ctrl->prefix |= ((unsigned long long)b) << shift;
      ctrl->rank_rem = (int)(r - cum);
      return;
    }
    cum += c;
  }
}

// Count keys < T; collect indices of keys == T (tie group).
__global__ void k_count(const unsigned long long* __restrict__ keys, int N,
                        Ctrl* ctrl, int* __restrict__ tieIdx) {
  __shared__ int sL;
  if (threadIdx.x == 0) sL = 0;
  __syncthreads();
  int e = blockIdx.x * blockDim.x + threadIdx.x;
  if (e < N) {
    unsigned long long k = keys[e];
    unsigned long long T = ctrl->prefix;
    if (k < T) {
      atomicAdd(&sL, 1);
    } else if (k == T) {
      int p = atomicAdd(&ctrl->tie_count, 1);
      if (p < TIECAP) tieIdx[p] = e;
    }
  }
  __syncthreads();
  if (threadIdx.x == 0 && sL) atomicAdd(&ctrl->L, sL);
}

// Kept iff key > T, or key == T with index-rank (within tie group) >= j,
// where j = num_rm - L ties must be pruned (stable argsort => smallest indices).
__device__ __forceinline__ bool is_kept(unsigned long long k, int e,
                                        const Ctrl* __restrict__ ctrl,
                                        const int* __restrict__ tieIdx) {
  unsigned long long T = ctrl->prefix;
  if (k < T) return false;
  if (k > T) return true;
  int j = ctrl->num_rm - ctrl->L;
  if (j <= 0) return true;
  int tc = ctrl->tie_count;
  if (tc > TIECAP) tc = TIECAP;
  int rank = 0;
  for (int i = 0; i < tc; ++i) rank += (tieIdx[i] < e) ? 1 : 0;
  return rank >= j;
}

// Per-block (1024) exclusive scan of kept flags; write block totals.
__global__ void k_scanA(const unsigned long long* __restrict__ keys, int N,
                        const Ctrl* __restrict__ ctrl, const int* __restrict__ tieIdx,
                        int* __restrict__ pos, int* __restrict__ blockSums) {
  __shared__ int sh[1024];
  int e = blockIdx.x * 1024 + threadIdx.x;
  int m = 0;
  if (e < N) m = is_kept(keys[e], e, ctrl, tieIdx) ? 1 : 0;
  sh[threadIdx.x] = m;
  __syncthreads();
  for (int off = 1; off < 1024; off <<= 1) {
    int v = sh[threadIdx.x];
    int add = (threadIdx.x >= (unsigned)off) ? sh[threadIdx.x - off] : 0;
    __syncthreads();
    sh[threadIdx.x] = v + add;
    __syncthreads();
  }
  if (e < N) pos[e] = sh[threadIdx.x] - m;  // exclusive in-block
  if (threadIdx.x == 1023) blockSums[blockIdx.x] = sh[1023];
}

// Serial exclusive scan of block sums (nb <= 256, trivial).
__global__ void k_scanB(int* blockSums, int nb) {
  if (threadIdx.x != 0 || blockIdx.x != 0) return;
  int acc = 0;
  for (int i = 0; i < nb; ++i) {
    int v = blockSums[i];
    blockSums[i] = acc;
    acc += v;
  }
}

// Gather kept columns for all batches; write edge_index (as float), edge_attr, mask.
__global__ void k_gather(const unsigned long long* __restrict__ keys,
                         const int* __restrict__ pos, const int* __restrict__ blockSums,
                         const Ctrl* __restrict__ ctrl, const int* __restrict__ tieIdx,
                         const int* __restrict__ ei, const float* __restrict__ attr,
                         long long E, int N, int Kkeep, int B,
                         float* __restrict__ out) {
  int e = blockIdx.x * blockDim.x + threadIdx.x;
  int b = blockIdx.y;
  if (e >= N) return;
  unsigned long long k = keys[e];
  bool kept = is_kept(k, e, ctrl, tieIdx);
  long long BK = (long long)B * Kkeep;
  if (b == 0) out[3 * BK + e] = kept ? 1.0f : 0.0f;  // mask output
  if (!kept) return;
  int kk = pos[e] + blockSums[e >> 10];
  long long col = (long long)b * N + e;
  float v0 = (float)ei[col];        // row 0 of edge_index
  float v1 = (float)ei[E + col];    // row 1 of edge_index
  float va = attr[col];
  long long o = (long long)b * Kkeep + kk;
  out[o] = v0;
  out[BK + o] = v1;
  out[2 * BK + o] = va;
}

extern "C" void kernel_launch(void* const* d_in, const int* in_sizes, int n_in,
                              void* d_out, int out_size, void* d_ws, size_t ws_size,
                              hipStream_t stream) {
  const int* ei = (const int*)d_in[0];
  const float* attr = (const float*)d_in[1];
  const float* wm = (const float*)d_in[3];

  int B = in_sizes[2] - 1;                       // 64
  long long E = (long long)in_sizes[0] / 2;      // 16777216
  int e_per = (int)(E / B);                      // 262144
  int D = (int)llround(sqrt((double)in_sizes[3]));  // 4096
  int num_rm = (int)((double)e_per * 0.3);       // 78643 (matches Python int())
  int Kkeep = e_per - num_rm;                    // 183501

  char* w = (char*)d_ws;
  size_t off = 0;
  unsigned long long* keys = (unsigned long long*)(w + off); off += (size_t)e_per * 8;
  unsigned int* hist8 = (unsigned int*)(w + off);            off += 8 * 256 * 4;
  int* pos = (int*)(w + off);                                off += (size_t)e_per * 4;
  int nb = (e_per + 1023) / 1024;
  int* blockSums = (int*)(w + off);                          off += (size_t)nb * 4;
  int* tieIdx = (int*)(w + off);                             off += (size_t)TIECAP * 4;
  Ctrl* ctrl = (Ctrl*)(w + off);                             off += sizeof(Ctrl);
  (void)ws_size; (void)n_in; (void)out_size;

  k_init<<<dim3(2), dim3(1024), 0, stream>>>(hist8, ctrl, num_rm);
  k_keys<<<dim3((e_per + 255) / 256), dim3(256), 0, stream>>>(ei, wm, e_per, E, D, keys);
  for (int l = 0; l < 8; ++l) {
    k_hist<<<dim3(nb), dim3(1024), 0, stream>>>(keys, e_per, l, ctrl, hist8 + l * 256);
    k_pick<<<dim3(1), dim3(64), 0, stream>>>(hist8 + l * 256, l, ctrl);
  }
  k_count<<<dim3(nb), dim3(1024), 0, stream>>>(keys, e_per, ctrl, tieIdx);
  k_scanA<<<dim3(nb), dim3(1024), 0, stream>>>(keys, e_per, ctrl, tieIdx, pos, blockSums);
  k_scanB<<<dim3(1), dim3(64), 0, stream>>>(blockSums, nb);
  dim3 gg((e_per + 255) / 256, B);
  k_gather<<<gg, dim3(256), 0, stream>>>(keys, pos, blockSums, ctrl, tieIdx,
                                         ei, attr, E, e_per, Kkeep, B, (float*)d_out);
}

// Round 2
// 135.839 us; speedup vs baseline: 2.0493x; 2.0493x over previous
//
#include <hip/hip_runtime.h>
#include <stdint.h>
#include <math.h>

#define TIECAP 4096
typedef unsigned long long ull;

struct Ctrl {
  ull prefix;      // accumulates selected key (threshold T)
  int rank_rem;    // remaining 0-indexed rank within matching subset
  int tie_count;   // count of keys == T
  int num_rm;
};

// Map double -> uint64 so unsigned compare == double ascending compare.
__device__ __forceinline__ ull dkey(double d) {
  ull u = (ull)__double_as_longlong(d);
  return (u & 0x8000000000000000ull) ? ~u : (u | 0x8000000000000000ull);
}

__global__ void k_init(unsigned int* hist8, Ctrl* ctrl, int num_rm) {
  int t = blockIdx.x * blockDim.x + threadIdx.x;
  if (t < 8 * 256) hist8[t] = 0u;
  if (t == 0) {
    ctrl->prefix = 0ull;
    ctrl->rank_rem = num_rm - 1;  // 0-indexed rank of largest pruned key
    ctrl->tie_count = 0;
    ctrl->num_rm = num_rm;
  }
}

// keys[e] = orderable bits of exact f64 sum wm[src,dst]+wm[dst,src]; fused level-0 hist.
__global__ void k_keys(const int* __restrict__ ei, const float* __restrict__ wm,
                       int N, long long E, int D,
                       ull* __restrict__ keys, unsigned int* __restrict__ hist0) {
  __shared__ unsigned int sh[256];
  if (threadIdx.x < 256) sh[threadIdx.x] = 0u;
  __syncthreads();
  int e = blockIdx.x * blockDim.x + threadIdx.x;
  if (e < N) {
    int src = ei[e];
    int dst = ei[E + e];
    double s = (double)wm[(long long)src * D + dst] + (double)wm[(long long)dst * D + src];
    ull k = dkey(s);
    keys[e] = k;
    atomicAdd(&sh[(unsigned int)(k >> 56)], 1u);
  }
  __syncthreads();
  if (threadIdx.x < 256 && sh[threadIdx.x]) atomicAdd(&hist0[threadIdx.x], sh[threadIdx.x]);
}

// Histogram of 8-bit digit `level` among elements whose higher bits match prefix.
__global__ void k_hist(const ull* __restrict__ keys, int N, int level,
                       const Ctrl* __restrict__ ctrl, unsigned int* __restrict__ hist) {
  __shared__ unsigned int sh[256];
  if (threadIdx.x < 256) sh[threadIdx.x] = 0u;
  __syncthreads();
  int e = blockIdx.x * blockDim.x + threadIdx.x;
  int shift = 56 - 8 * level;
  if (e < N) {
    ull k = keys[e];
    ull prefix = ctrl->prefix;
    if (((k ^ prefix) >> (shift + 8)) == 0ull)
      atomicAdd(&sh[(unsigned int)(k >> shift) & 0xFFu], 1u);
  }
  __syncthreads();
  if (threadIdx.x < 256 && sh[threadIdx.x]) atomicAdd(&hist[threadIdx.x], sh[threadIdx.x]);
}

// Parallel pick: 256-thread block scans 256 bins, finds bin containing rank.
__global__ void k_pick(const unsigned int* __restrict__ hist, int level, Ctrl* ctrl) {
  __shared__ unsigned int sh[256];
  int t = threadIdx.x;
  unsigned int c = hist[t];
  sh[t] = c;
  __syncthreads();
  for (int off = 1; off < 256; off <<= 1) {
    unsigned int v = sh[t];
    unsigned int a = (t >= off) ? sh[t - off] : 0u;
    __syncthreads();
    sh[t] = v + a;
    __syncthreads();
  }
  unsigned int incl = sh[t];
  unsigned int excl = incl - c;
  unsigned int r = (unsigned int)ctrl->rank_rem;
  if (r >= excl && r < incl) {
    int shift = 56 - 8 * level;
    ctrl->prefix |= ((ull)t) << shift;
    ctrl->rank_rem = (int)(r - excl);
  }
}

// Collect indices of keys == T (unordered; rank resolved by index compare later).
__global__ void k_ties(const ull* __restrict__ keys, int N, Ctrl* ctrl,
                       int* __restrict__ tieIdx) {
  int e = blockIdx.x * blockDim.x + threadIdx.x;
  if (e >= N) return;
  if (keys[e] == ctrl->prefix) {
    int p = atomicAdd(&ctrl->tie_count, 1);
    if (p < TIECAP) tieIdx[p] = e;
  }
}

// Kept iff key > T, or key == T and index-rank within tie group >= j,
// where j = rank_rem_final + 1 = num_rm - L (stable argsort semantics).
__device__ __forceinline__ bool is_kept(ull k, int e, ull T, int j, int tc,
                                        const int* __restrict__ tieIdx) {
  if (k < T) return false;
  if (k > T) return true;
  if (j <= 0) return true;
  if (tc > TIECAP) tc = TIECAP;
  int rank = 0;
  for (int i = 0; i < tc; ++i) rank += (tieIdx[i] < e) ? 1 : 0;
  return rank >= j;
}

// Per-block exclusive scan of kept flags; pos packs (excl<<1)|kept; writes mask output.
__global__ void k_scanA(const ull* __restrict__ keys, int N,
                        const Ctrl* __restrict__ ctrl, const int* __restrict__ tieIdx,
                        int* __restrict__ pos, int* __restrict__ blockSums,
                        float* __restrict__ mask_out) {
  __shared__ int sh[1024];
  ull T = ctrl->prefix;
  int j = ctrl->rank_rem + 1;
  int tc = ctrl->tie_count;
  int e = blockIdx.x * 1024 + threadIdx.x;
  int m = 0;
  if (e < N) m = is_kept(keys[e], e, T, j, tc, tieIdx) ? 1 : 0;
  sh[threadIdx.x] = m;
  __syncthreads();
  for (int off = 1; off < 1024; off <<= 1) {
    int v = sh[threadIdx.x];
    int add = (threadIdx.x >= (unsigned)off) ? sh[threadIdx.x - off] : 0;
    __syncthreads();
    sh[threadIdx.x] = v + add;
    __syncthreads();
  }
  if (e < N) {
    pos[e] = ((sh[threadIdx.x] - m) << 1) | m;
    mask_out[e] = m ? 1.0f : 0.0f;
  }
  if (threadIdx.x == 1023) blockSums[blockIdx.x] = sh[1023];
}

// Parallel exclusive scan of 256 block sums.
__global__ void k_scanB(int* bs, int nb) {
  __shared__ int sh[256];
  int t = threadIdx.x;
  int v = (t < nb) ? bs[t] : 0;
  sh[t] = v;
  __syncthreads();
  for (int off = 1; off < 256; off <<= 1) {
    int x = sh[t];
    int a = (t >= off) ? sh[t - off] : 0;
    __syncthreads();
    sh[t] = x + a;
    __syncthreads();
  }
  if (t < nb) bs[t] = sh[t] - v;
}

// Write compacted kept-index list: kidx[kk] = e (ascending e).
__global__ void k_kidx(const int* __restrict__ pos, const int* __restrict__ blockSums,
                       int N, int* __restrict__ kidx) {
  int e = blockIdx.x * blockDim.x + threadIdx.x;
  if (e >= N) return;
  int p = pos[e];
  if (p & 1) kidx[(p >> 1) + blockSums[e >> 10]] = e;
}

// Output-centric gather: one thread per aligned float4 slot of the 3*B*Kkeep output.
__global__ void k_gather(const int* __restrict__ kidx, const int* __restrict__ ei,
                         const float* __restrict__ attr, long long E, int N,
                         int Kkeep, long long BK, long long total4,
                         float* __restrict__ out) {
  long long q = (long long)blockIdx.x * blockDim.x + threadIdx.x;
  if (q >= total4) return;
  long long f = q * 4;
  int row = (f >= 2 * BK) ? 2 : ((f >= BK) ? 1 : 0);
  int rb = (int)(f - (long long)row * BK);
  int b = rb / Kkeep;
  int kk = rb - b * Kkeep;
  long long colbase = (long long)b * N;
  if (kk + 4 <= Kkeep) {
    int i0 = kidx[kk], i1 = kidx[kk + 1], i2 = kidx[kk + 2], i3 = kidx[kk + 3];
    float4 v;
    if (row == 0) {
      v.x = (float)ei[colbase + i0]; v.y = (float)ei[colbase + i1];
      v.z = (float)ei[colbase + i2]; v.w = (float)ei[colbase + i3];
    } else if (row == 1) {
      const int* p = ei + E;
      v.x = (float)p[colbase + i0]; v.y = (float)p[colbase + i1];
      v.z = (float)p[colbase + i2]; v.w = (float)p[colbase + i3];
    } else {
      v.x = attr[colbase + i0]; v.y = attr[colbase + i1];
      v.z = attr[colbase + i2]; v.w = attr[colbase + i3];
    }
    *(float4*)(out + f) = v;
  } else {
    // straddles a batch boundary: scalar fallback
    for (int i = 0; i < 4; ++i) {
      long long ff = f + i;
      int row2 = (ff >= 2 * BK) ? 2 : ((ff >= BK) ? 1 : 0);
      int rb2 = (int)(ff - (long long)row2 * BK);
      int b2 = rb2 / Kkeep;
      int kk2 = rb2 - b2 * Kkeep;
      int id = kidx[kk2];
      long long c = (long long)b2 * N + id;
      float v = (row2 == 0) ? (float)ei[c] : (row2 == 1) ? (float)ei[E + c] : attr[c];
      out[ff] = v;
    }
  }
}

extern "C" void kernel_launch(void* const* d_in, const int* in_sizes, int n_in,
                              void* d_out, int out_size, void* d_ws, size_t ws_size,
                              hipStream_t stream) {
  const int* ei = (const int*)d_in[0];
  const float* attr = (const float*)d_in[1];
  const float* wm = (const float*)d_in[3];

  int B = in_sizes[2] - 1;                          // 64
  long long E = (long long)in_sizes[0] / 2;         // 16777216
  int e_per = (int)(E / B);                         // 262144
  int D = (int)llround(sqrt((double)in_sizes[3]));  // 4096
  int num_rm = (int)((double)e_per * 0.3);          // 78643
  int Kkeep = e_per - num_rm;                       // 183501
  long long BK = (long long)B * Kkeep;
  long long total4 = 3 * BK / 4;                    // 3*BK divisible by 4

  char* w = (char*)d_ws;
  size_t off = 0;
  ull* keys = (ull*)(w + off);            off += (size_t)e_per * 8;
  unsigned int* hist8 = (unsigned int*)(w + off); off += 8 * 256 * 4;
  int* pos = (int*)(w + off);             off += (size_t)e_per * 4;
  int nb = (e_per + 1023) / 1024;         // 256
  int* blockSums = (int*)(w + off);       off += (size_t)nb * 4;
  int* tieIdx = (int*)(w + off);          off += (size_t)TIECAP * 4;
  int* kidx = (int*)(w + off);            off += (size_t)Kkeep * 4;
  Ctrl* ctrl = (Ctrl*)(w + off);          off += sizeof(Ctrl);
  (void)ws_size; (void)n_in; (void)out_size;

  float* out = (float*)d_out;
  float* mask_out = out + 3 * BK;

  k_init<<<dim3(2), dim3(1024), 0, stream>>>(hist8, ctrl, num_rm);
  k_keys<<<dim3(nb), dim3(1024), 0, stream>>>(ei, wm, e_per, E, D, keys, hist8);
  k_pick<<<dim3(1), dim3(256), 0, stream>>>(hist8, 0, ctrl);
  for (int l = 1; l < 8; ++l) {
    k_hist<<<dim3(nb), dim3(1024), 0, stream>>>(keys, e_per, l, ctrl, hist8 + l * 256);
    k_pick<<<dim3(1), dim3(256), 0, stream>>>(hist8 + l * 256, l, ctrl);
  }
  k_ties<<<dim3(nb), dim3(1024), 0, stream>>>(keys, e_per, ctrl, tieIdx);
  k_scanA<<<dim3(nb), dim3(1024), 0, stream>>>(keys, e_per, ctrl, tieIdx, pos, blockSums, mask_out);
  k_scanB<<<dim3(1), dim3(256), 0, stream>>>(blockSums, nb);
  k_kidx<<<dim3(nb), dim3(1024), 0, stream>>>(pos, blockSums, e_per, kidx);
  int gblocks = (int)((total4 + 255) / 256);
  k_gather<<<dim3(gblocks), dim3(256), 0, stream>>>(kidx, ei, attr, E, e_per, Kkeep, BK, total4, out);
}